// Round 8
// baseline (386.859 us; speedup 1.0000x reference)
//
#include <hip/hip_runtime.h>

#define N_SUP 4096
#define N_QRY 8192
#define IN_DIM 784
#define EMB 512
#define NCLS 64
#define M_TOT (N_SUP + N_QRY)
#define NCHUNK 25   // ceil(784/32)
#define XCH 13      // ceil(784/64)

typedef _Float16 f16;
typedef _Float16 f16x8 __attribute__((ext_vector_type(8)));
typedef float f32x4 __attribute__((ext_vector_type(4)));

// async global->LDS, 16B per lane. LDS dest is wave-uniform base + lane*16.
#define GLDS16(gp, lp)                                                        \
    __builtin_amdgcn_global_load_lds(                                         \
        (const __attribute__((address_space(1))) void*)(gp),                  \
        (__attribute__((address_space(3))) void*)(lp), 16, 0, 0)

// load 8 consecutive fp32 and convert to f16x8
static __device__ __forceinline__ f16x8 cvt8(const float* p) {
    float4 a = *(const float4*)p;
    float4 b = *(const float4*)(p + 4);
    f16x8 v;
    v[0] = (f16)a.x; v[1] = (f16)a.y; v[2] = (f16)a.z; v[3] = (f16)a.w;
    v[4] = (f16)b.x; v[5] = (f16)b.y; v[6] = (f16)b.z; v[7] = (f16)b.w;
    return v;
}

// ---- fused prep: [0,200) Wb repack, [200,1224) label argmax,
//      [1224,1756) zero norms+Num+cnt (contiguous 2,179,072 B = 136,192 f4) ----
__global__ __launch_bounds__(256) void pre_enc(const float* __restrict__ W,
                                               const float* __restrict__ lab,
                                               f16* __restrict__ Wb,
                                               int* __restrict__ lbl,
                                               float4* __restrict__ zbase) {
    if (blockIdx.x < 200) {
        int g = blockIdx.x * 256 + threadIdx.x;      // 51200 frag-lanes
        if (g >= NCHUNK * 32 * 64) return;
        int chunk = g >> 11;
        int rem = g & 2047;
        int nbg = rem >> 6, lane = rem & 63;
        int n = nbg * 16 + (lane & 15);
        int kbase = chunk * 32 + (lane >> 4) * 8;
        f16x8 v;
#pragma unroll
        for (int j = 0; j < 8; ++j) {
            int k = kbase + j;
            v[j] = (k < IN_DIM) ? (f16)W[(size_t)k * EMB + n] : (f16)0.f;
        }
        *(f16x8*)(Wb + (size_t)g * 8) = v;
    } else if (blockIdx.x < 1224) {
        const int w = threadIdx.x >> 6, lane = threadIdx.x & 63;
        const int s = (blockIdx.x - 200) * 4 + w;
        float v = lab[(size_t)s * NCLS + lane];
        int c = lane;
#pragma unroll
        for (int off = 1; off < 64; off <<= 1) {
            float v2 = __shfl_xor(v, off);
            int c2 = __shfl_xor(c, off);
            if (v2 > v || (v2 == v && c2 < c)) { v = v2; c = c2; }
        }
        if (lane == 0) lbl[s] = c;
    } else {
        int idx = (blockIdx.x - 1224) * 256 + threadIdx.x;   // < 136192 exact
        zbase[idx] = (float4){0.f, 0.f, 0.f, 0.f};
    }
}

// ---- encode: 32 rows x 256 cols per block, grid 768 (3 blocks/CU). ----
__global__ __launch_bounds__(256) void encode(
    const float* __restrict__ sup, const float* __restrict__ qry,
    const f16* __restrict__ Wb, const float* __restrict__ bias,
    f16* __restrict__ E, float* __restrict__ norms)
{
    __shared__ __align__(16) f16 Xs[32][72];
    const int tid = threadIdx.x;
    const int w = tid >> 6, lane = tid & 63;
    const int q = lane >> 4, c16 = lane & 15;
    const int mb = blockIdx.x >> 1;
    const int ch = blockIdx.x & 1;
    const int m0 = mb * 32;
    const int rbase = (w & 1) * 16;
    const int nbg0 = ch * 16 + (w >> 1) * 8;
    const int cbase = nbg0 * 16;

    f32x4 acc[8];
#pragma unroll
    for (int nb = 0; nb < 8; ++nb) acc[nb] = (f32x4){0.f, 0.f, 0.f, 0.f};

    const int sr = tid >> 3;
    const int sq = tid & 7;
    const float* xrow;
    {
        int gr = m0 + sr;
        xrow = (gr < N_SUP) ? sup + (size_t)gr * IN_DIM
                            : qry + (size_t)(gr - N_SUP) * IN_DIM;
    }

    f16x8 xg = cvt8(xrow + sq * 8);

    for (int c = 0; c < XCH; ++c) {
        __syncthreads();
        *(f16x8*)&Xs[sr][sq * 8] = xg;
        __syncthreads();
        if (c + 1 < XCH) {
            int k = (c + 1) * 64 + sq * 8;
            xg = (k + 8 <= IN_DIM) ? cvt8(xrow + k) : (f16x8){0,0,0,0,0,0,0,0};
        }
#pragma unroll
        for (int kc = 0; kc < 2; ++kc) {
            int c32 = c * 2 + kc;
            if (c32 >= NCHUNK) break;
            f16x8 a = *(const f16x8*)&Xs[rbase + c16][kc * 32 + q * 8];
            const f16* wb = Wb + ((size_t)(c32 * 32 + nbg0) * 64 + lane) * 8;
#pragma unroll
            for (int nb = 0; nb < 8; ++nb) {
                f16x8 b = *(const f16x8*)(wb + (size_t)nb * 512);
                acc[nb] = __builtin_amdgcn_mfma_f32_16x16x32_f16(a, b, acc[nb], 0, 0, 0);
            }
        }
    }

    float nrm[4] = {0.f, 0.f, 0.f, 0.f};
#pragma unroll
    for (int nb = 0; nb < 8; ++nb) {
        int col = cbase + nb * 16 + c16;
        float bv = bias[col];
#pragma unroll
        for (int r = 0; r < 4; ++r) {
            int row = m0 + rbase + q * 4 + r;
            float v = acc[nb][r] + bv;
            E[(size_t)row * EMB + col] = (f16)v;
            nrm[r] += v * v;
        }
    }
#pragma unroll
    for (int r = 0; r < 4; ++r) {
        float v = nrm[r];
        v += __shfl_xor(v, 1); v += __shfl_xor(v, 2);
        v += __shfl_xor(v, 4); v += __shfl_xor(v, 8);
        if (c16 == 0) atomicAdd(&norms[m0 + rbase + q * 4 + r], v);
    }
}

// ---- fused post-encode: [0,1024) Sb swizzle, [1024,3072) anchor ----
__global__ __launch_bounds__(256) void post_enc(
    const f16* __restrict__ E, const float* __restrict__ norms,
    f16* __restrict__ Sb, float* __restrict__ manc)
{
    const int b = blockIdx.x;
    if (b < 1024) {
        int g = b * 256 + threadIdx.x;   // 262144 groups of 8 f16
        int s = g >> 6, lg = g & 63;
        f16x8 v = *(const f16x8*)(E + (size_t)s * EMB + lg * 8);
        *(f16x8*)(Sb + (size_t)s * EMB + ((lg ^ (s & 15)) * 8)) = v;
    } else {
        const int w = threadIdx.x >> 6, lane = threadIdx.x & 63;
        const int qrow = (b - 1024) * 4 + w;
        f16x8 qv = *(const f16x8*)(E + (size_t)(N_SUP + qrow) * EMB + lane * 8);
        f16x8 sv = *(const f16x8*)(E + lane * 8);
        float dot = 0.f;
#pragma unroll
        for (int j = 0; j < 8; ++j) dot += (float)qv[j] * (float)sv[j];
        dot += __shfl_xor(dot, 1);  dot += __shfl_xor(dot, 2);
        dot += __shfl_xor(dot, 4);  dot += __shfl_xor(dot, 8);
        dot += __shfl_xor(dot, 16); dot += __shfl_xor(dot, 32);
        if (lane == 0) {
            float d2 = fmaxf(norms[N_SUP + qrow] + norms[0] - 2.f * dot, 0.f);
            manc[qrow] = sqrtf(d2);
        }
    }
}

// QK over K=512 x 16 supports from ring-slot base S (static per call site)
#define QK16(S, a)                                                            \
    _Pragma("unroll")                                                         \
    for (int kc = 0; kc < 4; ++kc) {                                          \
        _Pragma("unroll")                                                     \
        for (int ksl = 0; ksl < 4; ++ksl) {                                   \
            const int lg = kc * 16 + ksl * 4 + q;                             \
            f16x8 b = *(const f16x8*)&(S)[c16 * EMB + ((lg ^ c16) * 8)];      \
            a = __builtin_amdgcn_mfma_f32_16x16x32_f16(qf[kc * 4 + ksl], b, a, 0, 0, 0); \
        }                                                                     \
    }

// one tile: counted-vmcnt boundary, prefetch t+2, QK, exp-epilogue,
// label scatter-add into LDS accumulator (replaces Lcs/Pt/PV machinery)
#define BODY(t, Srd, Siss, DO_ISSUE, VM)                                      \
    {                                                                         \
        asm volatile("s_waitcnt vmcnt(" #VM ")" ::: "memory");                \
        __builtin_amdgcn_s_barrier();                                         \
        __builtin_amdgcn_sched_barrier(0);                                    \
        if (DO_ISSUE) {                                                       \
            const f16* gsrc = sb_base + (size_t)((t) + 2) * 16 * EMB;         \
            _Pragma("unroll")                                                 \
            for (int i = 0; i < 4; ++i)                                       \
                GLDS16(gsrc + (size_t)(wslot + i * 64 + lane) * 8,            \
                       &(Siss)[(wslot + i * 64) * 8]);                        \
        }                                                                     \
        const int cls = Lb[(t) * 16 + c16];                                   \
        f32x4 a = (f32x4){0.f, 0.f, 0.f, 0.f};                                \
        QK16(Srd, a)                                                          \
        const float s2 = Sn[(t) * 16 + c16];                                  \
        _Pragma("unroll")                                                     \
        for (int r = 0; r < 4; ++r) {                                         \
            float d2 = fmaxf(q2[r] + s2 - 2.f * a[r], 0.f);                   \
            float p = __expf(mrow[r] - __builtin_amdgcn_sqrtf(d2));           \
            atomicAdd(&NumL[w * 16 + q * 4 + r][cls], p);                     \
        }                                                                     \
    }

// ---- attn v9: scatter-add PV + counted-vmcnt 3-ring + fused finalize.
// 5 schedule variants all pinned at 86-92us -> delete work instead:
// P*onehot(L) is a label scatter-add, not a matmul. Per tile the wave does
// {barrier, 16 ds_read+MFMA, 4x sqrt/exp, 4 ds_add_f32} and nothing else.
// fp32 LDS accumulation (more accurate than old f16 Pt path, no clamp).
// Last ss-block per qt (atomic ticket, release fence) normalizes -> out;
// finalize dispatch deleted. ----
__global__ __launch_bounds__(256, 2) void attn(
    const f16* __restrict__ E, const float* __restrict__ norms,
    const float* __restrict__ manc, const int* __restrict__ lbl,
    const f16* __restrict__ Sb, float* __restrict__ Num,
    int* __restrict__ cnt, float* __restrict__ out)
{
    __shared__ __align__(16) f16 Ss[3][16 * EMB];   // 48KB ring
    __shared__ float NumL[64][NCLS];                // 16KB block accumulator
    __shared__ float Sn[512];                       // support norms slice
    __shared__ int Lb[512];                         // support labels slice
    __shared__ int lastf;
    const int tid = threadIdx.x;
    const int w = tid >> 6, lane = tid & 63;
    const int q = lane >> 4, c16 = lane & 15;
    const int ss = blockIdx.x & 7;        // XCD %8 residency heuristic
    const int qt = blockIdx.x >> 3;

    float* NumLf = &NumL[0][0];
#pragma unroll
    for (int i = 0; i < 16; ++i) NumLf[tid + i * 256] = 0.f;
    Sn[tid]       = norms[ss * 512 + tid];
    Sn[256 + tid] = norms[ss * 512 + 256 + tid];
    Lb[tid]       = lbl[ss * 512 + tid];
    Lb[256 + tid] = lbl[ss * 512 + 256 + tid];

    // resident Q fragments (A-layout m=c16): 64 VGPRs
    f16x8 qf[16];
    const f16* qb = E + (size_t)(N_SUP + qt * 64 + w * 16 + c16) * EMB + q * 8;
#pragma unroll
    for (int ks = 0; ks < 16; ++ks) qf[ks] = *(const f16x8*)(qb + ks * 32);
    float q2[4], mrow[4];
#pragma unroll
    for (int r = 0; r < 4; ++r) {
        q2[r]   = norms[N_SUP + qt * 64 + w * 16 + q * 4 + r];
        mrow[r] = manc[qt * 64 + w * 16 + q * 4 + r];
    }

    const f16* sb_base = Sb + (size_t)(ss * 512) * EMB;
    const int wslot = w * 256;            // wave's 256-slot region (x16B)
    f16* const Ss0 = &Ss[0][0];
    f16* const Ss1 = &Ss[1][0];
    f16* const Ss2 = &Ss[2][0];

    // prologue: fill ring slots 0,1; publish LDS staging before first barrier
#pragma unroll
    for (int i = 0; i < 4; ++i)
        GLDS16(sb_base + (size_t)(wslot + i * 64 + lane) * 8,
               Ss0 + (wslot + i * 64) * 8);
#pragma unroll
    for (int i = 0; i < 4; ++i)
        GLDS16(sb_base + (size_t)(16 * EMB) + (size_t)(wslot + i * 64 + lane) * 8,
               Ss1 + (wslot + i * 64) * 8);
    asm volatile("s_waitcnt lgkmcnt(0)" ::: "memory");

    for (int g = 0; g < 10; ++g) {
        const int t0 = g * 3;
        BODY(t0,     Ss0, Ss2, 1, 4)
        BODY(t0 + 1, Ss1, Ss0, 1, 4)
        BODY(t0 + 2, Ss2, Ss1, 1, 4)
    }
    BODY(30, Ss0, Ss0, 0, 4)
    BODY(31, Ss1, Ss0, 0, 0)

    __syncthreads();
    // flush block accumulator to global partial sums
#pragma unroll
    for (int i = 0; i < 16; ++i) {
        int idx = tid + i * 256;
        atomicAdd(&Num[(size_t)(qt * 64) * NCLS + idx], NumLf[idx]);
    }
    __threadfence();                      // release our Num atomics
    if (tid == 0) lastf = (atomicAdd(cnt + qt, 1) == 7) ? 1 : 0;
    __syncthreads();
    if (lastf) {
        // 8th arrival: all contributions visible at the coherent point
        const float* Nq = Num + (size_t)(qt * 64) * NCLS;
        float* oq = out + (size_t)(qt * 64) * NCLS;
#pragma unroll
        for (int i = 0; i < 16; ++i) {
            int row = w * 16 + i;
            float v = Nq[row * NCLS + lane];
            float s = v;
            s += __shfl_xor(s, 1);  s += __shfl_xor(s, 2);  s += __shfl_xor(s, 4);
            s += __shfl_xor(s, 8);  s += __shfl_xor(s, 16); s += __shfl_xor(s, 32);
            oq[row * NCLS + lane] = v / s;
        }
    }
}

extern "C" void kernel_launch(void* const* d_in, const int* in_sizes, int n_in,
                              void* d_out, int out_size, void* d_ws, size_t ws_size,
                              hipStream_t stream) {
    (void)in_sizes; (void)n_in; (void)out_size; (void)ws_size;
    const float* sup  = (const float*)d_in[0];
    const float* qry  = (const float*)d_in[1];
    const float* lab  = (const float*)d_in[2];
    const float* Wenc = (const float*)d_in[3];
    const float* benc = (const float*)d_in[4];
    float* out = (float*)d_out;

    char* ws = (char*)d_ws;
    size_t off = 0;
    f16* Wb = (f16*)(ws + off);        off += (size_t)NCHUNK * 32 * 64 * 8 * 2; // 819200
    f16* E  = (f16*)(ws + off);        off += (size_t)M_TOT * EMB * 2;          // 12582912
    f16* Sb = (f16*)(ws + off);        off += (size_t)N_SUP * EMB * 2;          // 4194304
    int* lbl = (int*)(ws + off);       off += (size_t)N_SUP * 4;                // 16384
    float* manc = (float*)(ws + off);  off += (size_t)N_QRY * 4;                // 32768
    // the next three are zeroed as one span by pre_enc (2,179,072 B)
    float* norms = (float*)(ws + off); off += (size_t)M_TOT * 4;                // 49152
    float* Num = (float*)(ws + off);   off += (size_t)N_QRY * NCLS * 4;         // 2097152
    int* cnt = (int*)(ws + off);       off += (size_t)N_QRY / 64 * 4;           // 32768 (padded)

    pre_enc<<<1756, 256, 0, stream>>>(Wenc, lab, Wb, lbl, (float4*)norms);
    encode<<<M_TOT / 32 * 2, 256, 0, stream>>>(sup, qry, Wb, benc, E, norms);
    post_enc<<<3072, 256, 0, stream>>>(E, norms, Sb, manc);
    attn<<<N_QRY / 64 * 8, 256, 0, stream>>>(E, norms, manc, lbl, Sb, Num, cnt, out);
}

// Round 9
// 266.035 us; speedup vs baseline: 1.4542x; 1.4542x over previous
//
#include <hip/hip_runtime.h>

#define N_SUP 4096
#define N_QRY 8192
#define IN_DIM 784
#define EMB 512
#define NCLS 64
#define M_TOT (N_SUP + N_QRY)
#define NCHUNK 25   // ceil(784/32)
#define XCH 13      // ceil(784/64)

typedef _Float16 f16;
typedef _Float16 f16x8 __attribute__((ext_vector_type(8)));
typedef float f32x4 __attribute__((ext_vector_type(4)));

// async global->LDS, 16B per lane. LDS dest is wave-uniform base + lane*16.
#define GLDS16(gp, lp)                                                        \
    __builtin_amdgcn_global_load_lds(                                         \
        (const __attribute__((address_space(1))) void*)(gp),                  \
        (__attribute__((address_space(3))) void*)(lp), 16, 0, 0)

// counted-vmcnt phase boundary (T3+T4): wait N-newest-allowed, block barrier,
// full scheduling fence so no LDS read hoists above it.
#define WAITB(N)                                                              \
    asm volatile("s_waitcnt vmcnt(" #N ")" ::: "memory");                     \
    __builtin_amdgcn_s_barrier();                                             \
    __builtin_amdgcn_sched_barrier(0);

// load 8 consecutive fp32 and convert to f16x8
static __device__ __forceinline__ f16x8 cvt8(const float* p) {
    float4 a = *(const float4*)p;
    float4 b = *(const float4*)(p + 4);
    f16x8 v;
    v[0] = (f16)a.x; v[1] = (f16)a.y; v[2] = (f16)a.z; v[3] = (f16)a.w;
    v[4] = (f16)b.x; v[5] = (f16)b.y; v[6] = (f16)b.z; v[7] = (f16)b.w;
    return v;
}

// ---- fused prep: [0,200) Wb repack, [200,1224) label argmax,
//      [1224,1756) zero norms+Num+cnt (contiguous 2,179,072 B) ----
__global__ __launch_bounds__(256) void pre_enc(const float* __restrict__ W,
                                               const float* __restrict__ lab,
                                               f16* __restrict__ Wb,
                                               int* __restrict__ lbl,
                                               float4* __restrict__ zbase) {
    if (blockIdx.x < 200) {
        int g = blockIdx.x * 256 + threadIdx.x;      // 51200 frag-lanes
        if (g >= NCHUNK * 32 * 64) return;
        int chunk = g >> 11;
        int rem = g & 2047;
        int nbg = rem >> 6, lane = rem & 63;
        int n = nbg * 16 + (lane & 15);
        int kbase = chunk * 32 + (lane >> 4) * 8;
        f16x8 v;
#pragma unroll
        for (int j = 0; j < 8; ++j) {
            int k = kbase + j;
            v[j] = (k < IN_DIM) ? (f16)W[(size_t)k * EMB + n] : (f16)0.f;
        }
        *(f16x8*)(Wb + (size_t)g * 8) = v;
    } else if (blockIdx.x < 1224) {
        const int w = threadIdx.x >> 6, lane = threadIdx.x & 63;
        const int s = (blockIdx.x - 200) * 4 + w;
        float v = lab[(size_t)s * NCLS + lane];
        int c = lane;
#pragma unroll
        for (int off = 1; off < 64; off <<= 1) {
            float v2 = __shfl_xor(v, off);
            int c2 = __shfl_xor(c, off);
            if (v2 > v || (v2 == v && c2 < c)) { v = v2; c = c2; }
        }
        if (lane == 0) lbl[s] = c;
    } else {
        int idx = (blockIdx.x - 1224) * 256 + threadIdx.x;   // 136192 exact
        zbase[idx] = (float4){0.f, 0.f, 0.f, 0.f};
    }
}

// ---- encode: 32 rows x 256 cols per block, grid 768 (3 blocks/CU). ----
__global__ __launch_bounds__(256) void encode(
    const float* __restrict__ sup, const float* __restrict__ qry,
    const f16* __restrict__ Wb, const float* __restrict__ bias,
    f16* __restrict__ E, float* __restrict__ norms)
{
    __shared__ __align__(16) f16 Xs[32][72];
    const int tid = threadIdx.x;
    const int w = tid >> 6, lane = tid & 63;
    const int q = lane >> 4, c16 = lane & 15;
    const int mb = blockIdx.x >> 1;
    const int ch = blockIdx.x & 1;
    const int m0 = mb * 32;
    const int rbase = (w & 1) * 16;
    const int nbg0 = ch * 16 + (w >> 1) * 8;
    const int cbase = nbg0 * 16;

    f32x4 acc[8];
#pragma unroll
    for (int nb = 0; nb < 8; ++nb) acc[nb] = (f32x4){0.f, 0.f, 0.f, 0.f};

    const int sr = tid >> 3;
    const int sq = tid & 7;
    const float* xrow;
    {
        int gr = m0 + sr;
        xrow = (gr < N_SUP) ? sup + (size_t)gr * IN_DIM
                            : qry + (size_t)(gr - N_SUP) * IN_DIM;
    }

    f16x8 xg = cvt8(xrow + sq * 8);

    for (int c = 0; c < XCH; ++c) {
        __syncthreads();
        *(f16x8*)&Xs[sr][sq * 8] = xg;
        __syncthreads();
        if (c + 1 < XCH) {
            int k = (c + 1) * 64 + sq * 8;
            xg = (k + 8 <= IN_DIM) ? cvt8(xrow + k) : (f16x8){0,0,0,0,0,0,0,0};
        }
#pragma unroll
        for (int kc = 0; kc < 2; ++kc) {
            int c32 = c * 2 + kc;
            if (c32 >= NCHUNK) break;
            f16x8 a = *(const f16x8*)&Xs[rbase + c16][kc * 32 + q * 8];
            const f16* wb = Wb + ((size_t)(c32 * 32 + nbg0) * 64 + lane) * 8;
#pragma unroll
            for (int nb = 0; nb < 8; ++nb) {
                f16x8 b = *(const f16x8*)(wb + (size_t)nb * 512);
                acc[nb] = __builtin_amdgcn_mfma_f32_16x16x32_f16(a, b, acc[nb], 0, 0, 0);
            }
        }
    }

    float nrm[4] = {0.f, 0.f, 0.f, 0.f};
#pragma unroll
    for (int nb = 0; nb < 8; ++nb) {
        int col = cbase + nb * 16 + c16;
        float bv = bias[col];
#pragma unroll
        for (int r = 0; r < 4; ++r) {
            int row = m0 + rbase + q * 4 + r;
            float v = acc[nb][r] + bv;
            E[(size_t)row * EMB + col] = (f16)v;
            nrm[r] += v * v;
        }
    }
#pragma unroll
    for (int r = 0; r < 4; ++r) {
        float v = nrm[r];
        v += __shfl_xor(v, 1); v += __shfl_xor(v, 2);
        v += __shfl_xor(v, 4); v += __shfl_xor(v, 8);
        if (c16 == 0) atomicAdd(&norms[m0 + rbase + q * 4 + r], v);
    }
}

// ---- post-encode: [0,1024) Sb swizzle, [1024,2048) Lcs one-hot transpose ----
__global__ __launch_bounds__(256) void post_enc(
    const f16* __restrict__ E, const int* __restrict__ lbl,
    f16* __restrict__ Sb, f16* __restrict__ Lcs)
{
    const int b = blockIdx.x;
    if (b < 1024) {
        int g = b * 256 + threadIdx.x;   // 262144 groups of 8 f16
        int s = g >> 6, lg = g & 63;
        f16x8 v = *(const f16x8*)(E + (size_t)s * EMB + lg * 8);
        *(f16x8*)(Sb + (size_t)s * EMB + ((lg ^ (s & 15)) * 8)) = v;
    } else {
        int idx = (b - 1024) * 256 + threadIdx.x;   // 262144 = NCLS*N_SUP
        int c = idx >> 12, s = idx & (N_SUP - 1);
        Lcs[idx] = (lbl[s] == c) ? (f16)1.f : (f16)0.f;
    }
}

// ---- attn v10: v8 core (86.2us champion: 4-ring, counted vmcnt(8), Pt/PV)
// + in-kernel anchor (d(q,s0) from resident qf: 16 f16x8 dots + 2 shuffles +
// 64B LDS bounce, once per block) + v9-verified ticket finalize.
// Deletes the anchor phase, manc buffer, and the finalize dispatch. ----
__global__ __launch_bounds__(256, 2) void attn(
    const f16* __restrict__ E, const float* __restrict__ norms,
    const f16* __restrict__ Lcs, const f16* __restrict__ Sb,
    float* __restrict__ Num, int* __restrict__ cnt, float* __restrict__ out)
{
    __shared__ __align__(16) f16 Ss[4][16 * EMB];   // 4 x 16KB ring
    __shared__ __align__(16) f16 Pt[4][16][40];     // per-wave P transpose, 5KB
    __shared__ float Sn[512];                       // support norms slice, 2KB
    __shared__ float Manc[4][16];                   // per-wave anchor bounce
    __shared__ int lastf;
    const int tid = threadIdx.x;
    const int w = tid >> 6, lane = tid & 63;
    const int q = lane >> 4, c16 = lane & 15;
    const int ss = blockIdx.x & 7;        // XCD %8 residency heuristic
    const int qt = blockIdx.x >> 3;

    // stage this slice's support norms once (published by first WAITB barrier)
    Sn[tid]       = norms[ss * 512 + tid];
    Sn[256 + tid] = norms[ss * 512 + 256 + tid];

    // resident Q fragments (A-layout m=c16): 64 VGPRs
    f16x8 qf[16];
    const f16* qb = E + (size_t)(N_SUP + qt * 64 + w * 16 + c16) * EMB + q * 8;
#pragma unroll
    for (int ks = 0; ks < 16; ++ks) qf[ks] = *(const f16x8*)(qb + ks * 32);

    // in-register anchor: d(row c16, support 0). Row c16's k-slices live in
    // this lane's qf; sum partials then reduce over q (lane bits 4,5).
    {
        float n0 = norms[0];
        float dp = 0.f;
        const f16* s0p = E + q * 8;
#pragma unroll
        for (int ks = 0; ks < 16; ++ks) {
            f16x8 sv = *(const f16x8*)(s0p + ks * 32);
#pragma unroll
            for (int j = 0; j < 8; ++j) dp += (float)qf[ks][j] * (float)sv[j];
        }
        dp += __shfl_xor(dp, 16);
        dp += __shfl_xor(dp, 32);
        float qn = norms[N_SUP + qt * 64 + w * 16 + c16];
        // 4 q-lanes write the same value to the same slot (benign)
        Manc[w][c16] = __builtin_amdgcn_sqrtf(fmaxf(qn + n0 - 2.f * dp, 0.f));
    }
    float q2[4], mrow[4];
#pragma unroll
    for (int r = 0; r < 4; ++r) {
        q2[r]   = norms[N_SUP + qt * 64 + w * 16 + q * 4 + r];
        mrow[r] = Manc[w][q * 4 + r];   // same-wave LDS RAW: DS is in-order
    }

    f32x4 accPL[4];
#pragma unroll
    for (int nb = 0; nb < 4; ++nb) accPL[nb] = (f32x4){0.f, 0.f, 0.f, 0.f};

    const f16* sb_base = Sb + (size_t)(ss * 512) * EMB;
    const int wslot = w * 256;            // wave's 256-slot region (x16B)

    auto ISSUE = [&](int tt) {            // 4 GLDS16 -> Ss[tt&3]
        const f16* gsrc = sb_base + (size_t)tt * 16 * EMB;
#pragma unroll
        for (int i = 0; i < 4; ++i)
            GLDS16(gsrc + (size_t)(wslot + i * 64 + lane) * 8,
                   &Ss[tt & 3][(wslot + i * 64) * 8]);
    };
    auto BL = [&](int p, f16x8* bl) {     // Lcs B-frags for pair p
        const int ps0 = ss * 512 + p * 32;
#pragma unroll
        for (int nbc = 0; nbc < 4; ++nbc)
            bl[nbc] = *(const f16x8*)(Lcs + (size_t)(nbc * 16 + c16) * N_SUP + ps0 + q * 8);
    };
    auto QK = [&](int t) -> f32x4 {       // K=512 x 16 supports from Ss[t&3]
        f32x4 a = (f32x4){0.f, 0.f, 0.f, 0.f};
        const f16* S = &Ss[t & 3][0];
#pragma unroll
        for (int kc = 0; kc < 4; ++kc)
#pragma unroll
            for (int ksl = 0; ksl < 4; ++ksl) {
                const int lg = kc * 16 + ksl * 4 + q;
                f16x8 b = *(const f16x8*)&S[c16 * EMB + ((lg ^ c16) * 8)];
                a = __builtin_amdgcn_mfma_f32_16x16x32_f16(qf[kc * 4 + ksl], b, a, 0, 0, 0);
            }
        return a;
    };
    auto EPI = [&](f32x4 acc, int t) {    // p = exp(m - d) -> Pt half
        const float s2 = Sn[t * 16 + c16];
        const int pcol = (t & 1) * 16 + c16;
#pragma unroll
        for (int r = 0; r < 4; ++r) {
            float d2 = fmaxf(q2[r] + s2 - 2.f * acc[r], 0.f);
            float p = __expf(mrow[r] - __builtin_amdgcn_sqrtf(d2));
            Pt[w][q * 4 + r][pcol] = (f16)fminf(p, 60000.f);
        }
    };
    auto PV = [&](const f16x8* bl) {      // K=32 (two tiles' P) x 4 class-grps
        f16x8 af = *(const f16x8*)&Pt[w][c16][q * 8];
#pragma unroll
        for (int nbc = 0; nbc < 4; ++nbc)
            accPL[nbc] = __builtin_amdgcn_mfma_f32_16x16x32_f16(af, bl[nbc], accPL[nbc], 0, 0, 0);
    };

    // prologue: fill 3 ring slots; drain LDS writes before first barrier
    ISSUE(0); ISSUE(1); ISSUE(2);
    asm volatile("s_waitcnt lgkmcnt(0)" ::: "memory");

    f16x8 bl[4];
    for (int tp = 0; tp < 14; ++tp) {
        const int t0 = tp * 2;
        WAITB(8);                          // batch t0 ready (t0+1,t0+2 in flight)
        BL(tp, bl);
        ISSUE(t0 + 3);
        EPI(QK(t0), t0);
        WAITB(8);                          // batch t0+1 ready
        ISSUE(t0 + 4);
        EPI(QK(t0 + 1), t0 + 1);
        PV(bl);
    }
    // peel tiles 28..31 (ring drain: vmcnt 8,8,4,0)
    WAITB(8); BL(14, bl); ISSUE(31); EPI(QK(28), 28);
    WAITB(8); EPI(QK(29), 29); PV(bl);
    WAITB(4); BL(15, bl); EPI(QK(30), 30);
    WAITB(0); EPI(QK(31), 31); PV(bl);

#pragma unroll
    for (int nbc = 0; nbc < 4; ++nbc)
#pragma unroll
        for (int r = 0; r < 4; ++r)
            atomicAdd(&Num[(size_t)(qt * 64 + w * 16 + q * 4 + r) * NCLS + nbc * 16 + c16],
                      accPL[nbc][r]);

    // ticket finalize (v9-verified): 8th ss-block per qt normalizes -> out
    __threadfence();                      // release our Num atomics
    if (tid == 0) lastf = (atomicAdd(cnt + qt, 1) == 7) ? 1 : 0;
    __syncthreads();
    if (lastf) {
        const float* Nq = Num + (size_t)(qt * 64) * NCLS;
        float* oq = out + (size_t)(qt * 64) * NCLS;
#pragma unroll
        for (int i = 0; i < 16; ++i) {
            int row = w * 16 + i;
            float v = Nq[row * NCLS + lane];
            float s = v;
            s += __shfl_xor(s, 1);  s += __shfl_xor(s, 2);  s += __shfl_xor(s, 4);
            s += __shfl_xor(s, 8);  s += __shfl_xor(s, 16); s += __shfl_xor(s, 32);
            oq[row * NCLS + lane] = v / s;
        }
    }
}

extern "C" void kernel_launch(void* const* d_in, const int* in_sizes, int n_in,
                              void* d_out, int out_size, void* d_ws, size_t ws_size,
                              hipStream_t stream) {
    (void)in_sizes; (void)n_in; (void)out_size; (void)ws_size;
    const float* sup  = (const float*)d_in[0];
    const float* qry  = (const float*)d_in[1];
    const float* lab  = (const float*)d_in[2];
    const float* Wenc = (const float*)d_in[3];
    const float* benc = (const float*)d_in[4];
    float* out = (float*)d_out;

    char* ws = (char*)d_ws;
    size_t off = 0;
    f16* Wb = (f16*)(ws + off);        off += (size_t)NCHUNK * 32 * 64 * 8 * 2; // 819200
    f16* E  = (f16*)(ws + off);        off += (size_t)M_TOT * EMB * 2;          // 12582912
    f16* Sb = (f16*)(ws + off);        off += (size_t)N_SUP * EMB * 2;          // 4194304
    int* lbl = (int*)(ws + off);       off += (size_t)N_SUP * 4;                // 16384
    f16* Lcs = (f16*)(ws + off);       off += (size_t)NCLS * N_SUP * 2;         // 524288
    // next three zeroed as one span by pre_enc (2,179,072 B exact)
    float* norms = (float*)(ws + off); off += (size_t)M_TOT * 4;                // 49152
    float* Num = (float*)(ws + off);   off += (size_t)N_QRY * NCLS * 4;         // 2097152
    int* cnt = (int*)(ws + off);       off += 32768;                            // padded

    pre_enc<<<1756, 256, 0, stream>>>(Wenc, lab, Wb, lbl, (float4*)norms);
    encode<<<M_TOT / 32 * 2, 256, 0, stream>>>(sup, qry, Wb, benc, E, norms);
    post_enc<<<2048, 256, 0, stream>>>(E, lbl, Sb, Lcs);
    attn<<<N_QRY / 64 * 8, 256, 0, stream>>>(E, norms, Lcs, Sb, Num, cnt, out);
}

// Round 10
// 201.517 us; speedup vs baseline: 1.9197x; 1.3202x over previous
//
#include <hip/hip_runtime.h>

#define N_SUP 4096
#define N_QRY 8192
#define IN_DIM 784
#define EMB 512
#define NCLS 64
#define M_TOT (N_SUP + N_QRY)
#define NCHUNK 25   // ceil(784/32)
#define XCH 13      // ceil(784/64)

typedef _Float16 f16;
typedef _Float16 f16x8 __attribute__((ext_vector_type(8)));
typedef float f32x4 __attribute__((ext_vector_type(4)));

// async global->LDS, 16B per lane. LDS dest is wave-uniform base + lane*16.
#define GLDS16(gp, lp)                                                        \
    __builtin_amdgcn_global_load_lds(                                         \
        (const __attribute__((address_space(1))) void*)(gp),                  \
        (__attribute__((address_space(3))) void*)(lp), 16, 0, 0)

// load 8 consecutive fp32 and convert to f16x8
static __device__ __forceinline__ f16x8 cvt8(const float* p) {
    float4 a = *(const float4*)p;
    float4 b = *(const float4*)(p + 4);
    f16x8 v;
    v[0] = (f16)a.x; v[1] = (f16)a.y; v[2] = (f16)a.z; v[3] = (f16)a.w;
    v[4] = (f16)b.x; v[5] = (f16)b.y; v[6] = (f16)b.z; v[7] = (f16)b.w;
    return v;
}

// ---- prep: W (784x512 fp32) -> Wb in MFMA B-frag order ----
__global__ __launch_bounds__(256) void prep_wb(const float* __restrict__ W,
                                               f16* __restrict__ Wb) {
    int g = blockIdx.x * 256 + threadIdx.x;          // 51200 frag-lanes
    if (g >= NCHUNK * 32 * 64) return;
    int chunk = g >> 11;
    int rem = g & 2047;
    int nbg = rem >> 6, lane = rem & 63;
    int n = nbg * 16 + (lane & 15);
    int kbase = chunk * 32 + (lane >> 4) * 8;
    f16x8 v;
#pragma unroll
    for (int j = 0; j < 8; ++j) {
        int k = kbase + j;
        v[j] = (k < IN_DIM) ? (f16)W[(size_t)k * EMB + n] : (f16)0.f;
    }
    *(f16x8*)(Wb + (size_t)g * 8) = v;
}

// ---- prep: one-hot labels -> argmax, wave-per-row (coalesced) ----
__global__ __launch_bounds__(256) void prep_lbl(const float* __restrict__ lab,
                                                int* __restrict__ lbl) {
    const int w = threadIdx.x >> 6, lane = threadIdx.x & 63;
    const int s = blockIdx.x * 4 + w;
    float v = lab[(size_t)s * NCLS + lane];
    int c = lane;
#pragma unroll
    for (int off = 1; off < 64; off <<= 1) {
        float v2 = __shfl_xor(v, off);
        int c2 = __shfl_xor(c, off);
        if (v2 > v || (v2 == v && c2 < c)) { v = v2; c = c2; }
    }
    if (lane == 0) lbl[s] = c;
}

// ---- prep: Lcs[c][s] one-hot transpose (coalesced reads+writes) ----
__global__ __launch_bounds__(256) void prep_L(const int* __restrict__ lbl,
                                              f16* __restrict__ Lcs) {
    int idx = blockIdx.x * 256 + threadIdx.x;
    if (idx >= NCLS * N_SUP) return;
    int c = idx >> 12, s = idx & (N_SUP - 1);
    Lcs[idx] = (lbl[s] == c) ? (f16)1.f : (f16)0.f;
}

// ---- prep: support E rows -> bank-swizzled Sb.
// Sb[s*512 + (lg ^ (s&15))*8 + j] = E[s*512 + lg*8 + j]
// The ds_read pattern in attn applies the same XOR -> uniform 8 dwords/bank.
__global__ __launch_bounds__(256) void prep_sb(const f16* __restrict__ E,
                                               f16* __restrict__ Sb) {
    int g = blockIdx.x * 256 + threadIdx.x;   // 262144 groups of 8 f16
    int s = g >> 6, lg = g & 63;
    f16x8 v = *(const f16x8*)(E + (size_t)s * EMB + lg * 8);
    *(f16x8*)(Sb + (size_t)s * EMB + ((lg ^ (s & 15)) * 8)) = v;
}

// ---- encode: 32 rows x 256 cols per block, grid 768 (3 blocks/CU). ----
__global__ __launch_bounds__(256) void encode(
    const float* __restrict__ sup, const float* __restrict__ qry,
    const f16* __restrict__ Wb, const float* __restrict__ bias,
    f16* __restrict__ E, float* __restrict__ norms)
{
    __shared__ __align__(16) f16 Xs[32][72];
    const int tid = threadIdx.x;
    const int w = tid >> 6, lane = tid & 63;
    const int q = lane >> 4, c16 = lane & 15;
    const int mb = blockIdx.x >> 1;
    const int ch = blockIdx.x & 1;
    const int m0 = mb * 32;
    const int rbase = (w & 1) * 16;
    const int nbg0 = ch * 16 + (w >> 1) * 8;
    const int cbase = nbg0 * 16;

    f32x4 acc[8];
#pragma unroll
    for (int nb = 0; nb < 8; ++nb) acc[nb] = (f32x4){0.f, 0.f, 0.f, 0.f};

    const int sr = tid >> 3;
    const int sq = tid & 7;
    const float* xrow;
    {
        int gr = m0 + sr;
        xrow = (gr < N_SUP) ? sup + (size_t)gr * IN_DIM
                            : qry + (size_t)(gr - N_SUP) * IN_DIM;
    }

    f16x8 xg = cvt8(xrow + sq * 8);

    for (int c = 0; c < XCH; ++c) {
        __syncthreads();
        *(f16x8*)&Xs[sr][sq * 8] = xg;
        __syncthreads();
        if (c + 1 < XCH) {
            int k = (c + 1) * 64 + sq * 8;
            xg = (k + 8 <= IN_DIM) ? cvt8(xrow + k) : (f16x8){0,0,0,0,0,0,0,0};
        }
#pragma unroll
        for (int kc = 0; kc < 2; ++kc) {
            int c32 = c * 2 + kc;
            if (c32 >= NCHUNK) break;
            f16x8 a = *(const f16x8*)&Xs[rbase + c16][kc * 32 + q * 8];
            const f16* wb = Wb + ((size_t)(c32 * 32 + nbg0) * 64 + lane) * 8;
#pragma unroll
            for (int nb = 0; nb < 8; ++nb) {
                f16x8 b = *(const f16x8*)(wb + (size_t)nb * 512);
                acc[nb] = __builtin_amdgcn_mfma_f32_16x16x32_f16(a, b, acc[nb], 0, 0, 0);
            }
        }
    }

    float nrm[4] = {0.f, 0.f, 0.f, 0.f};
#pragma unroll
    for (int nb = 0; nb < 8; ++nb) {
        int col = cbase + nb * 16 + c16;
        float bv = bias[col];
#pragma unroll
        for (int r = 0; r < 4; ++r) {
            int row = m0 + rbase + q * 4 + r;
            float v = acc[nb][r] + bv;
            E[(size_t)row * EMB + col] = (f16)v;
            nrm[r] += v * v;
        }
    }
#pragma unroll
    for (int r = 0; r < 4; ++r) {
        float v = nrm[r];
        v += __shfl_xor(v, 1); v += __shfl_xor(v, 2);
        v += __shfl_xor(v, 4); v += __shfl_xor(v, 8);
        if (c16 == 0) atomicAdd(&norms[m0 + rbase + q * 4 + r], v);
    }
}

// ---- anchor: m[q] = d(query q, support 0), wave-per-row ----
__global__ __launch_bounds__(256) void anchor(const f16* __restrict__ E,
                                              const float* __restrict__ norms,
                                              float* __restrict__ manc) {
    const int w = threadIdx.x >> 6, lane = threadIdx.x & 63;
    const int qrow = blockIdx.x * 4 + w;
    f16x8 qv = *(const f16x8*)(E + (size_t)(N_SUP + qrow) * EMB + lane * 8);
    f16x8 sv = *(const f16x8*)(E + lane * 8);
    float dot = 0.f;
#pragma unroll
    for (int j = 0; j < 8; ++j) dot += (float)qv[j] * (float)sv[j];
    dot += __shfl_xor(dot, 1);  dot += __shfl_xor(dot, 2);
    dot += __shfl_xor(dot, 4);  dot += __shfl_xor(dot, 8);
    dot += __shfl_xor(dot, 16); dot += __shfl_xor(dot, 32);
    if (lane == 0) {
        float d2 = fmaxf(norms[N_SUP + qrow] + norms[0] - 2.f * dot, 0.f);
        manc[qrow] = sqrtf(d2);
    }
}

// ---- attn v3: 16-support tiles (16KB dbuf) -> 4 blocks/CU via LDS (39.9KB).
// Champion config: measured 86.4us attn / 197.1us total. Six alternative
// schedules (T15 defer, dual-chain+setprio, 2x A-reuse, counted-vmcnt ring,
// LDS scatter-add PV, fused anchor/finalize) all measured 86-170us -> this
// structure is the empirical floor for this op on this chip. ----
__global__ __launch_bounds__(256, 3) void attn(
    const f16* __restrict__ E, const float* __restrict__ norms,
    const float* __restrict__ manc, const f16* __restrict__ Lcs,
    const f16* __restrict__ Sb, float* __restrict__ Num)
{
    __shared__ __align__(16) f16 Ss[2][16 * EMB];   // 2 x 16KB
    __shared__ __align__(16) f16 Pt[4][16][40];     // per-wave P transpose, 5KB
    __shared__ float Sn[512];                       // support norms slice, 2KB
    const int tid = threadIdx.x;
    const int w = tid >> 6, lane = tid & 63;
    const int q = lane >> 4, c16 = lane & 15;
    const int ss = blockIdx.x & 7;        // XCD %8 residency heuristic
    const int qt = blockIdx.x >> 3;

    // stage this slice's support norms once (epilogue reads LDS, not global)
    Sn[tid]       = norms[ss * 512 + tid];
    Sn[256 + tid] = norms[ss * 512 + 256 + tid];

    // resident Q fragments (A-layout m=c16): 64 VGPRs
    f16x8 qf[16];
    const f16* qb = E + (size_t)(N_SUP + qt * 64 + w * 16 + c16) * EMB + q * 8;
#pragma unroll
    for (int ks = 0; ks < 16; ++ks) qf[ks] = *(const f16x8*)(qb + ks * 32);
    float q2[4], mrow[4];
#pragma unroll
    for (int r = 0; r < 4; ++r) {
        q2[r]   = norms[N_SUP + qt * 64 + w * 16 + q * 4 + r];
        mrow[r] = manc[qt * 64 + w * 16 + q * 4 + r];
    }

    f32x4 accPL[4];
#pragma unroll
    for (int nb = 0; nb < 4; ++nb) accPL[nb] = (f32x4){0.f, 0.f, 0.f, 0.f};

    const f16* sb_base = Sb + (size_t)(ss * 512) * EMB;
    const int wslot = w * 256;            // wave's 256-slot region (x16B)

    // prologue: DMA tile 0 -> buf 0 (barrier also publishes Sn)
#pragma unroll
    for (int i = 0; i < 4; ++i)
        GLDS16(sb_base + (size_t)(wslot + i * 64 + lane) * 8,
               &Ss[0][(wslot + i * 64) * 8]);
    __syncthreads();

#pragma unroll 2
    for (int t = 0; t < 32; ++t) {
        const int cur = t & 1;
        if (t + 1 < 32) {
            const f16* gsrc = sb_base + (size_t)(t + 1) * 16 * EMB;
#pragma unroll
            for (int i = 0; i < 4; ++i)
                GLDS16(gsrc + (size_t)(wslot + i * 64 + lane) * 8,
                       &Ss[cur ^ 1][(wslot + i * 64) * 8]);
        }
        // odd tile: issue Lcs B-frag loads for this pair early (L2-hot;
        // latency covered by the QK MFMA chain below)
        f16x8 bl[4];
        if (t & 1) {
            const int ps0 = ss * 512 + (t >> 1) * 32;
#pragma unroll
            for (int nbc = 0; nbc < 4; ++nbc)
                bl[nbc] = *(const f16x8*)(Lcs + (size_t)(nbc * 16 + c16) * N_SUP + ps0 + q * 8);
        }

        // QK over full K=512 for 16 supports
        f32x4 accQK = (f32x4){0.f, 0.f, 0.f, 0.f};
#pragma unroll
        for (int kc = 0; kc < 4; ++kc) {
#pragma unroll
            for (int ksl = 0; ksl < 4; ++ksl) {
                const int lg = kc * 16 + ksl * 4 + q;
                f16x8 b = *(const f16x8*)&Ss[cur][c16 * EMB + ((lg ^ c16) * 8)];
                accQK = __builtin_amdgcn_mfma_f32_16x16x32_f16(
                    qf[kc * 4 + ksl], b, accQK, 0, 0, 0);
            }
        }
        // epilogue: p = exp(m - d) -> Pt half (wave-private, DS pipe in-order)
        {
            const float s2 = Sn[t * 16 + c16];
            const int pcol = (t & 1) * 16 + c16;
#pragma unroll
            for (int r = 0; r < 4; ++r) {
                float d2 = fmaxf(q2[r] + s2 - 2.f * accQK[r], 0.f);
                float p = __expf(mrow[r] - __builtin_amdgcn_sqrtf(d2));
                p = fminf(p, 60000.f);     // f16-overflow guard
                Pt[w][q * 4 + r][pcol] = (f16)p;
            }
        }
        // PV: one K=32 chunk (two tiles' P) against 4 class-groups
        if (t & 1) {
            f16x8 af = *(const f16x8*)&Pt[w][c16][q * 8];
#pragma unroll
            for (int nbc = 0; nbc < 4; ++nbc)
                accPL[nbc] = __builtin_amdgcn_mfma_f32_16x16x32_f16(af, bl[nbc], accPL[nbc], 0, 0, 0);
        }

        __syncthreads();   // drains DMA(t+1) + syncs buffer swap
    }

#pragma unroll
    for (int nbc = 0; nbc < 4; ++nbc)
#pragma unroll
        for (int r = 0; r < 4; ++r)
            atomicAdd(&Num[(size_t)(qt * 64 + w * 16 + q * 4 + r) * NCLS + nbc * 16 + c16],
                      accPL[nbc][r]);
}

// ---- finalize: out[q][c] = Num[q][c] / rowsum(Num[q]) ----
__global__ __launch_bounds__(256) void finalize(const float* __restrict__ Num,
                                                float* __restrict__ out) {
    const int tid = threadIdx.x;
    const int w = tid >> 6, lane = tid & 63;
    const int qrow = blockIdx.x * 4 + w;
    float v = Num[(size_t)qrow * NCLS + lane];
    float s = v;
    s += __shfl_xor(s, 1);  s += __shfl_xor(s, 2);  s += __shfl_xor(s, 4);
    s += __shfl_xor(s, 8);  s += __shfl_xor(s, 16); s += __shfl_xor(s, 32);
    out[(size_t)qrow * NCLS + lane] = v / s;
}

extern "C" void kernel_launch(void* const* d_in, const int* in_sizes, int n_in,
                              void* d_out, int out_size, void* d_ws, size_t ws_size,
                              hipStream_t stream) {
    (void)in_sizes; (void)n_in; (void)out_size; (void)ws_size;
    const float* sup  = (const float*)d_in[0];
    const float* qry  = (const float*)d_in[1];
    const float* lab  = (const float*)d_in[2];
    const float* Wenc = (const float*)d_in[3];
    const float* benc = (const float*)d_in[4];
    float* out = (float*)d_out;

    char* ws = (char*)d_ws;
    size_t off = 0;
    f16* Wb = (f16*)(ws + off);        off += (size_t)NCHUNK * 32 * 64 * 8 * 2; // 819200
    f16* E  = (f16*)(ws + off);        off += (size_t)M_TOT * EMB * 2;          // 12582912
    f16* Sb = (f16*)(ws + off);        off += (size_t)N_SUP * EMB * 2;          // 4194304
    int* lbl = (int*)(ws + off);       off += (size_t)N_SUP * 4;                // 16384
    f16* Lcs = (f16*)(ws + off);       off += (size_t)NCLS * N_SUP * 2;         // 524288
    float* manc = (float*)(ws + off);  off += (size_t)N_QRY * 4;                // 32768
    float* norms = (float*)(ws + off); off += (size_t)M_TOT * 4;                // 49152
    float* Num = (float*)(ws + off);   off += (size_t)N_QRY * NCLS * 4;         // 2097152

    // norms and Num adjacent: one memset
    hipMemsetAsync(norms, 0, (size_t)M_TOT * 4 + (size_t)N_QRY * NCLS * 4, stream);

    prep_wb<<<(NCHUNK * 32 * 64 + 255) / 256, 256, 0, stream>>>(Wenc, Wb);
    prep_lbl<<<N_SUP / 4, 256, 0, stream>>>(lab, lbl);
    prep_L<<<NCLS * N_SUP / 256, 256, 0, stream>>>(lbl, Lcs);
    encode<<<M_TOT / 32 * 2, 256, 0, stream>>>(sup, qry, Wb, benc, E, norms);
    prep_sb<<<N_SUP * 64 / 256, 256, 0, stream>>>(E, Sb);
    anchor<<<N_QRY / 4, 256, 0, stream>>>(E, norms, manc);
    attn<<<N_QRY / 64 * 8, 256, 0, stream>>>(E, norms, manc, Lcs, Sb, Num);
    finalize<<<N_QRY / 4, 256, 0, stream>>>(Num, out);
}